// Round 11
// baseline (84.062 us; speedup 1.0000x reference)
//
#include <hip/hip_runtime.h>

typedef __attribute__((ext_vector_type(8))) short short8;
typedef __attribute__((ext_vector_type(4))) float f32x4;

#define KPAD 40     // gates kernel B chunk row: 32 data + 8 pad shorts

// workspace layout (bytes)
#define WS_HID 0u        // 256*256 f32  = 262144
#define WS_P   262144u   // 131072 f32   = 524288
#define WS_Z   786432u   // 256 f32      = 1024
#define WS_CTX 802816u   // 65536 f32    = 262144
#define WS_WBF 1064960u  // 8192 x 16B   = 131072 (ends 1196032)

__device__ __forceinline__ unsigned cvtpk(float lo, float hi) {
    unsigned r;
    asm("v_cvt_pk_bf16_f32 %0, %1, %2" : "=v"(r) : "v"(lo), "v"(hi));
    return r;
}
__device__ __forceinline__ int4 pack8(float4 x0, float4 x1) {
    int4 q;
    q.x = (int)cvtpk(x0.x, x0.y);
    q.y = (int)cvtpk(x0.z, x0.w);
    q.z = (int)cvtpk(x1.x, x1.y);
    q.w = (int)cvtpk(x1.z, x1.w);
    return q;
}
__device__ __forceinline__ float tanh_fast(float x) {
    float e2 = __expf(2.f * x);
    return 1.f - 2.f * __builtin_amdgcn_rcpf(e2 + 1.f);
}
__device__ __forceinline__ float sigmoid_fast(float x) {
    return __builtin_amdgcn_rcpf(1.f + __expf(-x));
}
__device__ __forceinline__ void gload16(const void* g, void* l) {
    __builtin_amdgcn_global_load_lds((const __attribute__((address_space(1))) void*)g,
                                     (__attribute__((address_space(3))) void*)l, 16, 0, 0);
}

// ---------------- K0: hid GEMV + W_i2h -> frag-order bf16 ----------------
// Wbf unit u (16B): u = cf*512 + ks*64 + lane holds bf16 of
// W_i2h[n = cf*16 + (lane&15)][k = ks*32 + (lane>>4)*8 .. +8]
// -> a wave's B-fragment is one contiguous 1KB read.
__global__ __launch_bounds__(256) void k_prep(
    const float* __restrict__ prev_h, const float* __restrict__ W_i2h,
    const float* __restrict__ W_h2h, const float* __restrict__ b_h2h,
    float* __restrict__ hid, int4* __restrict__ Wbf)
{
    int bid = blockIdx.x, tid = threadIdx.x;
    if (bid < 256) {                       // hid[b][h] = prev_h[b]·W_h2h[h] + b_h2h[h]
        __shared__ float ph[256];
        ph[tid] = prev_h[bid * 256 + tid];
        __syncthreads();
        float acc = b_h2h[tid];
        const float4* w = (const float4*)(W_h2h + tid * 256);
        #pragma unroll 8
        for (int k4 = 0; k4 < 64; ++k4) {
            float4 ww = w[k4];
            acc += ww.x * ph[k4*4+0] + ww.y * ph[k4*4+1] + ww.z * ph[k4*4+2] + ww.w * ph[k4*4+3];
        }
        hid[bid * 256 + tid] = acc;
    } else {                               // frag-order convert: 8192 units
        int u = (bid - 256) * 256 + tid;
        int cf = u >> 9, ks = (u >> 6) & 7;
        int n = cf * 16 + (u & 15);
        int k0 = ks * 32 + ((u >> 4) & 3) * 8;
        float4 x0 = *(const float4*)(W_i2h + n * 256 + k0);
        float4 x1 = *(const float4*)(W_i2h + n * 256 + k0 + 4);
        Wbf[u] = pack8(x0, x1);
    }
}

// ---------------- K1: e-scores + p=exp(e) + z (barrier-free streaming) ----------------
// 256 blocks (block = batch b) x 512 thr (8 waves). B panel (256x256 bf16 = 128KB,
// frag-order) DMA'd ONCE to LDS. Each wave independently streams 4 tiles of 16 bt-rows:
// issue 16 A-loads -> cvt_pk -> 8x16 MFMA (B via contiguous ds_read_b128) -> tanh/shfl
// epilogue. NO barriers in the loop: 8 free-running waves keep ~100KB/CU of HBM loads
// in flight (the R3-R10 designs drained to zero every tile).
__global__ __launch_bounds__(512, 2) void k_e(
    const float* __restrict__ BH, const int4* __restrict__ Wbf,
    const float* __restrict__ hid, const float* __restrict__ Wsc,
    float* __restrict__ p_out, float* __restrict__ zbuf)
{
    __shared__ short Blds[65536];      // 131072 B, frag-order B panel
    __shared__ float zsh[8];

    const int tid = threadIdx.x;
    const int lane = tid & 63;
    const int w8 = tid >> 6;           // wave 0..7
    const int l15 = lane & 15, lg = lane >> 4;
    const int b = blockIdx.x;

    // ---- A tile-0 loads issued first (HBM critical path) ----
    float4 la[16];
    auto issueA = [&](int tile) {
        const float* base = BH + ((size_t)b * 512 + tile * 16 + l15) * 256 + lg * 8;
        #pragma unroll
        for (int ks = 0; ks < 8; ++ks) {
            la[2 * ks]     = *(const float4*)(base + ks * 32);
            la[2 * ks + 1] = *(const float4*)(base + ks * 32 + 4);
        }
    };
    issueA(w8);

    // ---- B panel DMA: 16 rounds x 8KB ----
    {
        const char* g = (const char*)Wbf;
        char* l = (char*)Blds;
        #pragma unroll
        for (int rnd = 0; rnd < 16; ++rnd)
            gload16(g + rnd * 8192 + tid * 16, l + rnd * 8192 + tid * 16);
    }

    // ---- per-lane col constants: col = cf*16 + l15 ----
    float wsv[16], hd[16];
    #pragma unroll
    for (int cf = 0; cf < 16; ++cf) {
        wsv[cf] = Wsc[cf * 16 + l15];
        hd[cf]  = hid[b * 256 + cf * 16 + l15];
    }
    __syncthreads();   // drains B DMA (and tile-0 A loads)

    float zacc = 0.f;
    for (int ti = 0; ti < 4; ++ti) {
        const int tile = ti * 8 + w8;          // 0..31
        f32x4 acc[16];
        #pragma unroll
        for (int cf = 0; cf < 16; ++cf) acc[cf] = (f32x4){0.f, 0.f, 0.f, 0.f};

        #pragma unroll
        for (int ks = 0; ks < 8; ++ks) {
            short8 af; *(int4*)&af = pack8(la[2 * ks], la[2 * ks + 1]);
            #pragma unroll
            for (int cf = 0; cf < 16; ++cf) {
                short8 bfr = *(const short8*)&Blds[(cf * 512 + ks * 64 + lane) * 8];
                acc[cf] = __builtin_amdgcn_mfma_f32_16x16x32_bf16(af, bfr, acc[cf], 0, 0, 0);
            }
        }
        if (ti < 3) issueA(tile + 8);          // next tile's HBM loads fly under epilogue

        // epilogue: e = sum_col wsv*tanh(acc+hd); rows = lg*4+r
        float esum[4] = {0.f, 0.f, 0.f, 0.f};
        #pragma unroll
        for (int cf = 0; cf < 16; ++cf)
            #pragma unroll
            for (int r = 0; r < 4; ++r)
                esum[r] += wsv[cf] * tanh_fast(acc[cf][r] + hd[cf]);
        #pragma unroll
        for (int r = 0; r < 4; ++r) {
            float s = esum[r];
            s += __shfl_xor(s, 1); s += __shfl_xor(s, 2);
            s += __shfl_xor(s, 4); s += __shfl_xor(s, 8);
            esum[r] = s;                       // e[tile*16 + lg*4 + r], same across l15
        }
        float ps = 0.f, p4r[4];
        #pragma unroll
        for (int r = 0; r < 4; ++r) { p4r[r] = __expf(esum[r]); ps += p4r[r]; }
        if (l15 == 0) {
            #pragma unroll
            for (int r = 0; r < 4; ++r)
                p_out[b * 512 + tile * 16 + lg * 4 + r] = p4r[r];
        }
        ps += __shfl_xor(ps, 16); ps += __shfl_xor(ps, 32);   // sum over lg groups
        zacc += ps;
    }
    if (lane == 0) zsh[w8] = zacc;
    __syncthreads();
    if (tid == 0) {
        float z = 0.f;
        #pragma unroll
        for (int i = 0; i < 8; ++i) z += zsh[i];
        zbuf[b] = z;
    }
}

// ---------------- K2: normalize + alpha + context (streaming, L3-hot) ----------------
__global__ __launch_bounds__(256) void k_ctx(
    const float* __restrict__ p, const float* __restrict__ zbuf,
    const float* __restrict__ BH, float* __restrict__ alpha, float* __restrict__ ctx)
{
    __shared__ float pl[512];
    int b = blockIdx.x, t = threadIdx.x;
    pl[t] = p[b * 512 + t];
    pl[256 + t] = p[b * 512 + 256 + t];
    __syncthreads();
    float inv = 1.f / zbuf[b];
    alpha[b * 512 + t] = pl[t] * inv;
    alpha[b * 512 + 256 + t] = pl[256 + t] * inv;
    const float* bh = BH + (size_t)b * 512 * 256 + t;
    float acc = 0.f;
    #pragma unroll 16
    for (int tt = 0; tt < 512; ++tt) acc += pl[tt] * bh[(size_t)tt * 256];
    ctx[b * 256 + t] = acc * inv;
}

// ---------------- K3: gates GEMM (256x1024, K=608=19x32) fused with LSTM ----------------
__global__ __launch_bounds__(256) void k_gates_lstm(
    const float* __restrict__ ctx, const float* __restrict__ onehot,
    const float* __restrict__ prev_h, const float* __restrict__ W_ih,
    const float* __restrict__ W_hh, const float* __restrict__ b_ih,
    const float* __restrict__ b_hh, const float* __restrict__ prev_c,
    float* __restrict__ out)
{
    __shared__ char smem[20800];
    short* AlB = (short*)smem;            // [2][64*KPAD]
    short* BlB = (short*)smem + 5120;     // [2][64*KPAD]
    const int tid = threadIdx.x;
    const int lane = tid & 63;
    const int w = tid >> 6;
    const int l15 = lane & 15, lg = lane >> 4;
    const int rb = blockIdx.x * 64;
    const int hb = blockIdx.y;

    f32x4 acc[4];
    #pragma unroll
    for (int j = 0; j < 4; j++) acc[j] = (f32x4){0.f, 0.f, 0.f, 0.f};

    const int arow = tid >> 2, akg = tid & 3;
    const int rg = rb + arow;
    const int bn = tid >> 2, bq = tid & 3;
    const int np_ = hb * 64 + bn, hh_ = np_ >> 2, gg_ = np_ & 3;
    const float* wih_row = W_ih + (size_t)(gg_ * 256 + hh_) * 352;
    const float* whh_row = W_hh + (size_t)(gg_ * 256 + hh_) * 256;

    auto stageAB = [&](int kc, int bu) {
        int k0 = kc * 32 + akg * 8;
        const float4* pa;
        if (k0 < 256)      pa = (const float4*)(ctx    + rg * 256 + k0);
        else if (k0 < 352) pa = (const float4*)(onehot + rg * 96  + (k0 - 256));
        else               pa = (const float4*)(prev_h + rg * 256 + (k0 - 352));
        float4 x0 = pa[0], x1 = pa[1];
        *(int4*)&AlB[bu * 2560 + arow * KPAD + akg * 8] = pack8(x0, x1);
        int kb = kc * 32 + bq * 8;
        const float* pb = (kb < 352) ? (wih_row + kb) : (whh_row + (kb - 352));
        float4 y0 = *(const float4*)pb, y1 = *(const float4*)(pb + 4);
        *(int4*)&BlB[bu * 2560 + bn * KPAD + bq * 8] = pack8(y0, y1);
    };

    stageAB(0, 0);
    __syncthreads();

    for (int kc = 0; kc < 19; ++kc) {
        int cur = kc & 1;
        short8 af = *(const short8*)&AlB[cur * 2560 + (w * 16 + l15) * KPAD + lg * 8];
        short8 bfr[4];
        #pragma unroll
        for (int cf = 0; cf < 4; cf++)
            bfr[cf] = *(const short8*)&BlB[cur * 2560 + (cf * 16 + l15) * KPAD + lg * 8];
        if (kc < 18) stageAB(kc + 1, cur ^ 1);
        #pragma unroll
        for (int cf = 0; cf < 4; cf++)
            acc[cf] = __builtin_amdgcn_mfma_f32_16x16x32_bf16(af, bfr[cf], acc[cf], 0, 0, 0);
        __syncthreads();
    }

    float* Gt = (float*)smem;                    // [64][65]
    #pragma unroll
    for (int cf = 0; cf < 4; cf++) {
        int col = cf * 16 + l15;
        int np = hb * 64 + col;
        int hg = np >> 2, g = np & 3;
        float bias = b_ih[g * 256 + hg] + b_hh[g * 256 + hg];
        #pragma unroll
        for (int r = 0; r < 4; r++)
            Gt[(w * 16 + lg * 4 + r) * 65 + col] = acc[cf][r] + bias;
    }
    __syncthreads();

    #pragma unroll
    for (int it = 0; it < 4; ++it) {
        int elem = it * 256 + tid;               // < 1024
        int row = elem >> 4, hl = elem & 15;
        float gi = Gt[row * 65 + hl * 4 + 0];
        float gf = Gt[row * 65 + hl * 4 + 1];
        float gg = Gt[row * 65 + hl * 4 + 2];
        float go = Gt[row * 65 + hl * 4 + 3];
        int bg = rb + row, hglob = hb * 16 + hl;
        float cv = sigmoid_fast(gf) * prev_c[bg * 256 + hglob] + sigmoid_fast(gi) * tanh_fast(gg);
        out[bg * 256 + hglob] = sigmoid_fast(go) * tanh_fast(cv);
        out[65536 + bg * 256 + hglob] = cv;
    }
}

extern "C" void kernel_launch(void* const* d_in, const int* in_sizes, int n_in,
                              void* d_out, int out_size, void* d_ws, size_t ws_size,
                              hipStream_t stream) {
    (void)in_sizes; (void)n_in; (void)out_size; (void)ws_size;
    const float* prev_h  = (const float*)d_in[0];
    const float* prev_c  = (const float*)d_in[1];
    const float* batch_H = (const float*)d_in[2];
    const float* onehot  = (const float*)d_in[3];
    const float* W_i2h   = (const float*)d_in[4];
    const float* W_h2h   = (const float*)d_in[5];
    const float* b_h2h   = (const float*)d_in[6];
    const float* W_score = (const float*)d_in[7];
    const float* W_ih    = (const float*)d_in[8];
    const float* W_hh    = (const float*)d_in[9];
    const float* b_ih    = (const float*)d_in[10];
    const float* b_hh    = (const float*)d_in[11];

    char* ws = (char*)d_ws;
    float* hid   = (float*)(ws + WS_HID);
    float* p     = (float*)(ws + WS_P);
    float* zbuf  = (float*)(ws + WS_Z);
    float* ctx   = (float*)(ws + WS_CTX);
    int4*  Wbf   = (int4*)(ws + WS_WBF);

    float* out = (float*)d_out;
    float* alpha = out + 131072;            // h:[0,64K) c:[64K,128K) alpha:[128K,256K) floats

    hipLaunchKernelGGL(k_prep,       dim3(288),    dim3(256), 0, stream,
                       prev_h, W_i2h, W_h2h, b_h2h, hid, Wbf);
    hipLaunchKernelGGL(k_e,          dim3(256),    dim3(512), 0, stream,
                       batch_H, Wbf, hid, W_score, p, zbuf);
    hipLaunchKernelGGL(k_ctx,        dim3(256),    dim3(256), 0, stream,
                       p, zbuf, batch_H, alpha, ctx);
    hipLaunchKernelGGL(k_gates_lstm, dim3(4, 16),  dim3(256), 0, stream,
                       ctx, onehot, prev_h, W_ih, W_hh, b_ih, b_hh, prev_c, out);
}

// Round 12
// 77.643 us; speedup vs baseline: 1.0827x; 1.0827x over previous
//
#include <hip/hip_runtime.h>

typedef __attribute__((ext_vector_type(8))) short short8;
typedef __attribute__((ext_vector_type(4))) float f32x4;

#define KPAD 40     // gates kernel B chunk row: 32 data + 8 pad shorts

// workspace layout (bytes)
#define WS_HID 0u        // 256*256 f32  = 262144
#define WS_CTX 262144u   // 65536 f32    = 262144
#define WS_WBF 524288u   // 8192 x 16B   = 131072 (ends 655360)

__device__ __forceinline__ unsigned cvtpk(float lo, float hi) {
    unsigned r;
    asm("v_cvt_pk_bf16_f32 %0, %1, %2" : "=v"(r) : "v"(lo), "v"(hi));
    return r;
}
__device__ __forceinline__ int4 pack8(float4 x0, float4 x1) {
    int4 q;
    q.x = (int)cvtpk(x0.x, x0.y);
    q.y = (int)cvtpk(x0.z, x0.w);
    q.z = (int)cvtpk(x1.x, x1.y);
    q.w = (int)cvtpk(x1.z, x1.w);
    return q;
}
__device__ __forceinline__ float bf2f(unsigned s) {
    union { float f; unsigned u; } v; v.u = s << 16;
    return v.f;
}
__device__ __forceinline__ float tanh_fast(float x) {
    float e2 = __expf(2.f * x);
    return 1.f - 2.f * __builtin_amdgcn_rcpf(e2 + 1.f);
}
__device__ __forceinline__ float sigmoid_fast(float x) {
    return __builtin_amdgcn_rcpf(1.f + __expf(-x));
}
__device__ __forceinline__ void gload16(const void* g, void* l) {
    __builtin_amdgcn_global_load_lds((const __attribute__((address_space(1))) void*)g,
                                     (__attribute__((address_space(3))) void*)l, 16, 0, 0);
}

// ---------------- K0: hid GEMV + W_i2h -> frag-order bf16 ----------------
// Wbf unit u (16B): u = cf*512 + ks*64 + lane holds bf16 of
// W_i2h[n = cf*16 + (lane&15)][k = ks*32 + (lane>>4)*8 .. +8]
__global__ __launch_bounds__(256) void k_prep(
    const float* __restrict__ prev_h, const float* __restrict__ W_i2h,
    const float* __restrict__ W_h2h, const float* __restrict__ b_h2h,
    float* __restrict__ hid, int4* __restrict__ Wbf)
{
    int bid = blockIdx.x, tid = threadIdx.x;
    if (bid < 256) {                       // hid[b][h] = prev_h[b]·W_h2h[h] + b_h2h[h]
        __shared__ float ph[256];
        ph[tid] = prev_h[bid * 256 + tid];
        __syncthreads();
        float acc = b_h2h[tid];
        const float4* w = (const float4*)(W_h2h + tid * 256);
        #pragma unroll 8
        for (int k4 = 0; k4 < 64; ++k4) {
            float4 ww = w[k4];
            acc += ww.x * ph[k4*4+0] + ww.y * ph[k4*4+1] + ww.z * ph[k4*4+2] + ww.w * ph[k4*4+3];
        }
        hid[bid * 256 + tid] = acc;
    } else {                               // frag-order convert: 8192 units
        int u = (bid - 256) * 256 + tid;
        int cf = u >> 9, ks = (u >> 6) & 7;
        int n = cf * 16 + (u & 15);
        int k0 = ks * 32 + ((u >> 4) & 3) * 8;
        float4 x0 = *(const float4*)(W_i2h + n * 256 + k0);
        float4 x1 = *(const float4*)(W_i2h + n * 256 + k0 + 4);
        Wbf[u] = pack8(x0, x1);
    }
}

// ---------------- K1: FUSED attention: e -> p -> Z -> alpha, ctx ----------------
// 256 blocks (block = batch b) x 512 thr (8 waves). B (128KB frag-order) in LDS once.
// Waves free-run 4 tiles of 16 bt-rows each, ZERO barriers in the loop.
// A-loads: volatile-asm global_load_dwordx4 (issue point pinned — plain loads get
// sunk past the epilogue, killing prefetch; R4/R8/R9/R11 failure mode), consumed
// after s_waitcnt vmcnt(0) + sched_barrier(0) (rule: compiler hoists reg-only ops
// past asm waitcnt otherwise). p = exp(e) shift-free (|e| <= ||Wsc||_1 ~ 10).
// ctx accumulates IN-REGISTER from the bf16 A-frags (p known per-tile) — this
// deletes the separate 134MB ctx re-read kernel entirely.
__global__ __launch_bounds__(512, 2) void k_attn(
    const float* __restrict__ BH, const int4* __restrict__ Wbf,
    const float* __restrict__ hid, const float* __restrict__ Wsc,
    float* __restrict__ alpha, float* __restrict__ ctx)
{
    __shared__ short Blds[65536];          // 128 KB frag-order B panel
    __shared__ float hdl[256], wscl[256];
    __shared__ float pl8[8][16];
    __shared__ float r8[8][256];
    __shared__ float zsh[8];

    const int tid = threadIdx.x;
    const int lane = tid & 63;
    const int w8 = tid >> 6;               // wave 0..7
    const int l15 = lane & 15, lg = lane >> 4;
    const int b = blockIdx.x;

    int4 la[16];
    #define ISSUE_A(tile_)                                                          \
        {                                                                           \
            const float* base_ = BH + ((size_t)b * 512 + (tile_) * 16 + l15) * 256  \
                                 + lg * 8;                                          \
            asm volatile(                                                           \
                "global_load_dwordx4 %0, %16, off offset:0\n"                       \
                "global_load_dwordx4 %1, %16, off offset:16\n"                      \
                "global_load_dwordx4 %2, %16, off offset:128\n"                     \
                "global_load_dwordx4 %3, %16, off offset:144\n"                     \
                "global_load_dwordx4 %4, %16, off offset:256\n"                     \
                "global_load_dwordx4 %5, %16, off offset:272\n"                     \
                "global_load_dwordx4 %6, %16, off offset:384\n"                     \
                "global_load_dwordx4 %7, %16, off offset:400\n"                     \
                "global_load_dwordx4 %8, %16, off offset:512\n"                     \
                "global_load_dwordx4 %9, %16, off offset:528\n"                     \
                "global_load_dwordx4 %10, %16, off offset:640\n"                    \
                "global_load_dwordx4 %11, %16, off offset:656\n"                    \
                "global_load_dwordx4 %12, %16, off offset:768\n"                    \
                "global_load_dwordx4 %13, %16, off offset:784\n"                    \
                "global_load_dwordx4 %14, %16, off offset:896\n"                    \
                "global_load_dwordx4 %15, %16, off offset:912\n"                    \
                : "=v"(la[0]), "=v"(la[1]), "=v"(la[2]), "=v"(la[3]),               \
                  "=v"(la[4]), "=v"(la[5]), "=v"(la[6]), "=v"(la[7]),               \
                  "=v"(la[8]), "=v"(la[9]), "=v"(la[10]), "=v"(la[11]),             \
                  "=v"(la[12]), "=v"(la[13]), "=v"(la[14]), "=v"(la[15])            \
                : "v"(base_));                                                      \
        }

    ISSUE_A(w8);                           // tile 0 in flight

    // B panel DMA: 16 rounds x 8KB
    {
        const char* g = (const char*)Wbf;
        #pragma unroll
        for (int rnd = 0; rnd < 16; ++rnd)
            gload16(g + rnd * 8192 + tid * 16, (char*)Blds + rnd * 8192 + tid * 16);
    }
    if (tid < 256) { hdl[tid] = hid[b * 256 + tid]; wscl[tid] = Wsc[tid]; }
    __syncthreads();                       // drains B DMA + tile-0 A loads

    float ctxacc[64];
    #pragma unroll
    for (int i = 0; i < 64; ++i) ctxacc[i] = 0.f;
    float p4[4][4];
    float zacc = 0.f;

    #pragma unroll
    for (int ti = 0; ti < 4; ++ti) {
        const int tile = ti * 8 + w8;
        asm volatile("s_waitcnt vmcnt(0)" ::: "memory");
        __builtin_amdgcn_sched_barrier(0);
        short8 af[8];
        #pragma unroll
        for (int ks = 0; ks < 8; ++ks) {
            float4 f0, f1;
            *(int4*)&f0 = la[2 * ks];
            *(int4*)&f1 = la[2 * ks + 1];
            *(int4*)&af[ks] = pack8(f0, f1);
        }
        if (ti < 3) ISSUE_A(tile + 8);     // volatile: issues HERE, flies under MFMA

        float esum[4] = {0.f, 0.f, 0.f, 0.f};
        #pragma unroll
        for (int h2 = 0; h2 < 2; ++h2) {   // col halves -> acc only 32 VGPRs
            f32x4 acc[8];
            #pragma unroll
            for (int c = 0; c < 8; ++c) acc[c] = (f32x4){0.f, 0.f, 0.f, 0.f};
            #pragma unroll
            for (int ks = 0; ks < 8; ++ks)
                #pragma unroll
                for (int c = 0; c < 8; ++c)
                    acc[c] = __builtin_amdgcn_mfma_f32_16x16x32_bf16(af[ks],
                        *(const short8*)&Blds[(((h2 * 8 + c) * 512) + ks * 64 + lane) * 8],
                        acc[c], 0, 0, 0);
            #pragma unroll
            for (int c = 0; c < 8; ++c) {
                int col = (h2 * 8 + c) * 16 + l15;
                float wv = wscl[col], hv = hdl[col];
                #pragma unroll
                for (int r = 0; r < 4; ++r)
                    esum[r] += wv * tanh_fast(acc[c][r] + hv);
            }
        }
        #pragma unroll
        for (int r = 0; r < 4; ++r) {
            float s = esum[r];
            s += __shfl_xor(s, 1); s += __shfl_xor(s, 2);
            s += __shfl_xor(s, 4); s += __shfl_xor(s, 8);
            esum[r] = s;                   // e[tile*16 + lg*4 + r]
        }
        float ps = 0.f;
        #pragma unroll
        for (int r = 0; r < 4; ++r) { p4[ti][r] = __expf(esum[r]); ps += p4[ti][r]; }
        ps += __shfl_xor(ps, 16); ps += __shfl_xor(ps, 32);
        zacc += ps;
        if (l15 == 0) {
            #pragma unroll
            for (int r = 0; r < 4; ++r) pl8[w8][lg * 4 + r] = p4[ti][r];
        }
        float pv = pl8[w8][l15];           // same-wave LDS dep -> auto lgkmcnt
        #pragma unroll
        for (int ks = 0; ks < 8; ++ks)
            #pragma unroll
            for (int j = 0; j < 8; ++j)
                ctxacc[ks * 8 + j] += pv * bf2f((unsigned)(unsigned short)af[ks][j]);
    }

    if (lane == 0) zsh[w8] = zacc;
    // ctx: reduce over the 16 l15-lanes (same d, different rows)
    #pragma unroll
    for (int i = 0; i < 64; ++i) {
        float s = ctxacc[i];
        s += __shfl_xor(s, 1); s += __shfl_xor(s, 2);
        s += __shfl_xor(s, 4); s += __shfl_xor(s, 8);
        ctxacc[i] = s;
    }
    if (l15 == 0) {
        #pragma unroll
        for (int ks = 0; ks < 8; ++ks)
            #pragma unroll
            for (int j = 0; j < 8; ++j)
                r8[w8][ks * 32 + lg * 8 + j] = ctxacc[ks * 8 + j];
    }
    __syncthreads();
    float Z = 0.f;
    #pragma unroll
    for (int i = 0; i < 8; ++i) Z += zsh[i];
    const float inv = 1.f / Z;
    if (l15 == 0) {
        #pragma unroll
        for (int ti = 0; ti < 4; ++ti)
            #pragma unroll
            for (int r = 0; r < 4; ++r)
                alpha[b * 512 + (ti * 8 + w8) * 16 + lg * 4 + r] = p4[ti][r] * inv;
    }
    if (tid < 256) {
        float s = 0.f;
        #pragma unroll
        for (int ww = 0; ww < 8; ++ww) s += r8[ww][tid];
        ctx[b * 256 + tid] = s * inv;
    }
    #undef ISSUE_A
}

// ---------------- K2: gates GEMM (256x1024, K=608=19x32) fused with LSTM ----------------
__global__ __launch_bounds__(256) void k_gates_lstm(
    const float* __restrict__ ctx, const float* __restrict__ onehot,
    const float* __restrict__ prev_h, const float* __restrict__ W_ih,
    const float* __restrict__ W_hh, const float* __restrict__ b_ih,
    const float* __restrict__ b_hh, const float* __restrict__ prev_c,
    float* __restrict__ out)
{
    __shared__ char smem[20800];
    short* AlB = (short*)smem;            // [2][64*KPAD]
    short* BlB = (short*)smem + 5120;     // [2][64*KPAD]
    const int tid = threadIdx.x;
    const int lane = tid & 63;
    const int w = tid >> 6;
    const int l15 = lane & 15, lg = lane >> 4;
    const int rb = blockIdx.x * 64;
    const int hb = blockIdx.y;

    f32x4 acc[4];
    #pragma unroll
    for (int j = 0; j < 4; j++) acc[j] = (f32x4){0.f, 0.f, 0.f, 0.f};

    const int arow = tid >> 2, akg = tid & 3;
    const int rg = rb + arow;
    const int bn = tid >> 2, bq = tid & 3;
    const int np_ = hb * 64 + bn, hh_ = np_ >> 2, gg_ = np_ & 3;
    const float* wih_row = W_ih + (size_t)(gg_ * 256 + hh_) * 352;
    const float* whh_row = W_hh + (size_t)(gg_ * 256 + hh_) * 256;

    auto stageAB = [&](int kc, int bu) {
        int k0 = kc * 32 + akg * 8;
        const float4* pa;
        if (k0 < 256)      pa = (const float4*)(ctx    + rg * 256 + k0);
        else if (k0 < 352) pa = (const float4*)(onehot + rg * 96  + (k0 - 256));
        else               pa = (const float4*)(prev_h + rg * 256 + (k0 - 352));
        float4 x0 = pa[0], x1 = pa[1];
        *(int4*)&AlB[bu * 2560 + arow * KPAD + akg * 8] = pack8(x0, x1);
        int kb = kc * 32 + bq * 8;
        const float* pb = (kb < 352) ? (wih_row + kb) : (whh_row + (kb - 352));
        float4 y0 = *(const float4*)pb, y1 = *(const float4*)(pb + 4);
        *(int4*)&BlB[bu * 2560 + bn * KPAD + bq * 8] = pack8(y0, y1);
    };

    stageAB(0, 0);
    __syncthreads();

    for (int kc = 0; kc < 19; ++kc) {
        int cur = kc & 1;
        short8 af = *(const short8*)&AlB[cur * 2560 + (w * 16 + l15) * KPAD + lg * 8];
        short8 bfr[4];
        #pragma unroll
        for (int cf = 0; cf < 4; cf++)
            bfr[cf] = *(const short8*)&BlB[cur * 2560 + (cf * 16 + l15) * KPAD + lg * 8];
        if (kc < 18) stageAB(kc + 1, cur ^ 1);
        #pragma unroll
        for (int cf = 0; cf < 4; cf++)
            acc[cf] = __builtin_amdgcn_mfma_f32_16x16x32_bf16(af, bfr[cf], acc[cf], 0, 0, 0);
        __syncthreads();
    }

    float* Gt = (float*)smem;                    // [64][65]
    #pragma unroll
    for (int cf = 0; cf < 4; cf++) {
        int col = cf * 16 + l15;
        int np = hb * 64 + col;
        int hg = np >> 2, g = np & 3;
        float bias = b_ih[g * 256 + hg] + b_hh[g * 256 + hg];
        #pragma unroll
        for (int r = 0; r < 4; r++)
            Gt[(w * 16 + lg * 4 + r) * 65 + col] = acc[cf][r] + bias;
    }
    __syncthreads();

    #pragma unroll
    for (int it = 0; it < 4; ++it) {
        int elem = it * 256 + tid;               // < 1024
        int row = elem >> 4, hl = elem & 15;
        float gi = Gt[row * 65 + hl * 4 + 0];
        float gf = Gt[row * 65 + hl * 4 + 1];
        float gg = Gt[row * 65 + hl * 4 + 2];
        float go = Gt[row * 65 + hl * 4 + 3];
        int bg = rb + row, hglob = hb * 16 + hl;
        float cv = sigmoid_fast(gf) * prev_c[bg * 256 + hglob] + sigmoid_fast(gi) * tanh_fast(gg);
        out[bg * 256 + hglob] = sigmoid_fast(go) * tanh_fast(cv);
        out[65536 + bg * 256 + hglob] = cv;
    }
}

extern "C" void kernel_launch(void* const* d_in, const int* in_sizes, int n_in,
                              void* d_out, int out_size, void* d_ws, size_t ws_size,
                              hipStream_t stream) {
    (void)in_sizes; (void)n_in; (void)out_size; (void)ws_size;
    const float* prev_h  = (const float*)d_in[0];
    const float* prev_c  = (const float*)d_in[1];
    const float* batch_H = (const float*)d_in[2];
    const float* onehot  = (const float*)d_in[3];
    const float* W_i2h   = (const float*)d_in[4];
    const float* W_h2h   = (const float*)d_in[5];
    const float* b_h2h   = (const float*)d_in[6];
    const float* W_score = (const float*)d_in[7];
    const float* W_ih    = (const float*)d_in[8];
    const float* W_hh    = (const float*)d_in[9];
    const float* b_ih    = (const float*)d_in[10];
    const float* b_hh    = (const float*)d_in[11];

    char* ws = (char*)d_ws;
    float* hid = (float*)(ws + WS_HID);
    float* ctx = (float*)(ws + WS_CTX);
    int4*  Wbf = (int4*)(ws + WS_WBF);

    float* out = (float*)d_out;
    float* alpha = out + 131072;            // h:[0,64K) c:[64K,128K) alpha:[128K,256K) floats

    hipLaunchKernelGGL(k_prep,       dim3(288),   dim3(256), 0, stream,
                       prev_h, W_i2h, W_h2h, b_h2h, hid, Wbf);
    hipLaunchKernelGGL(k_attn,       dim3(256),   dim3(512), 0, stream,
                       batch_H, Wbf, hid, W_score, alpha, ctx);
    hipLaunchKernelGGL(k_gates_lstm, dim3(4, 16), dim3(256), 0, stream,
                       ctx, onehot, prev_h, W_ih, W_hh, b_ih, b_hh, prev_c, out);
}